// Round 18
// baseline (53.920 us; speedup 1.0000x reference)
//
#include <hip/hip_runtime.h>

#define NB     128
#define NCLS   19
#define HW     (512*512)
#define NPIX   (8*HW)
#define HSZ    (NCLS*NB)          // 2432 packed u32 counters per histogram copy (9.7 KB)
#define NCOPY  64                 // L2-resident global copies (622 KB total)
#define NBLK   2048               // hist grid; NBLK*256*4 == NPIX exactly (no loop)

typedef _Float16 half2_t __attribute__((ext_vector_type(2)));

// ---------------- K0: zero the 64 copies + accumulators ----------------
__global__ __launch_bounds__(256) void zero_kernel(unsigned* __restrict__ copies,
                                                   unsigned long long* __restrict__ acc,
                                                   unsigned* __restrict__ lock,
                                                   unsigned* __restrict__ npres) {
    int i = blockIdx.x * 256 + threadIdx.x;       // NCOPY*HSZ = 608*256 exact
    copies[i] = 0u;
    if (i == 0) { *acc = 0ull; *lock = 0u; *npres = 0u; }
}

// ---------------- K1: softmax + LDS histogram; 4 px/thread float4, half2-packed exps ----------------
// Deconfounded width test: R8's float4 failed via register pressure (105 VGPR ->
// 16 waves/CU). Here exps live as 38 packed u32 (v_cvt_pkrtz) = same budget as the
// 2-px f32 version -> full 8 blocks/CU occupancy AND dwordx4 loads (1 KB/class/wave).
// Half precision: rel err 5e-4 on p -> bucket shift <= 0.13 of 1/127 (R12: absmax 0.0).
// packed u32 bucket: low 16 = bg, high 16 = fg; per-copy budget 32*1024 px <= 65535.
__global__ __launch_bounds__(256) void hist_kernel(const float* __restrict__ logits,
                                                   const int* __restrict__ labels,
                                                   unsigned* __restrict__ copies) {
    __shared__ unsigned h[HSZ];
    for (int i = threadIdx.x; i < HSZ; i += 256) h[i] = 0u;
    __syncthreads();

    int p0 = (blockIdx.x * 256 + threadIdx.x) * 4;   // 4 consecutive pixels, 16B aligned
    int b  = p0 >> 18;                               // p0 / HW (HW = 2^18)
    int hw = p0 & (HW - 1);
    const float* base = logits + ((size_t)b * NCLS) * HW + hw;

    unsigned e01[NCLS], e23[NCLS];                   // half2(exp px0,px1), half2(px2,px3)
    float s0 = 0.f, s1 = 0.f, s2 = 0.f, s3 = 0.f;
#pragma unroll
    for (int c = 0; c < NCLS; ++c) {
        float4 z = *(const float4*)(base + (size_t)c * HW);   // coalesced 16B/lane
        float x0 = __expf(z.x);                      // no max-sub: |logit| < ~6 for N(0,1)
        float x1 = __expf(z.y);
        float x2 = __expf(z.z);
        float x3 = __expf(z.w);
        e01[c] = __builtin_bit_cast(unsigned, __builtin_amdgcn_cvt_pkrtz(x0, x1));
        e23[c] = __builtin_bit_cast(unsigned, __builtin_amdgcn_cvt_pkrtz(x2, x3));
        s0 += x0; s1 += x1; s2 += x2; s3 += x3;
    }
    float sc0 = (float)(NB - 1) * __builtin_amdgcn_rcpf(s0);
    float sc1 = (float)(NB - 1) * __builtin_amdgcn_rcpf(s1);
    float sc2 = (float)(NB - 1) * __builtin_amdgcn_rcpf(s2);
    float sc3 = (float)(NB - 1) * __builtin_amdgcn_rcpf(s3);
    int4 lb = *(const int4*)(labels + p0);

#pragma unroll
    for (int c = 0; c < NCLS; ++c) {
        half2_t p01 = __builtin_bit_cast(half2_t, e01[c]);
        half2_t p23 = __builtin_bit_cast(half2_t, e23[c]);
        // bg bucket: floor(pc*(NB-1)+0.5); fg: floor(NB - t) = round((1-pc)*(NB-1))
        float t0 = fmaf((float)p01.x, sc0, 0.5f);
        bool  f0 = (lb.x == c);
        t0 = f0 ? ((float)NB - t0) : t0;
        atomicAdd(&h[c * NB + (int)t0], f0 ? 0x10000u : 1u);

        float t1 = fmaf((float)p01.y, sc1, 0.5f);
        bool  f1 = (lb.y == c);
        t1 = f1 ? ((float)NB - t1) : t1;
        atomicAdd(&h[c * NB + (int)t1], f1 ? 0x10000u : 1u);

        float t2 = fmaf((float)p23.x, sc2, 0.5f);
        bool  f2 = (lb.z == c);
        t2 = f2 ? ((float)NB - t2) : t2;
        atomicAdd(&h[c * NB + (int)t2], f2 ? 0x10000u : 1u);

        float t3 = fmaf((float)p23.y, sc3, 0.5f);
        bool  f3 = (lb.w == c);
        t3 = f3 ? ((float)NB - t3) : t3;
        atomicAdd(&h[c * NB + (int)t3], f3 ? 0x10000u : 1u);
    }

    __syncthreads();
    // merge into one of NCOPY L2-resident copies with u64 atomics (2 buckets/op)
    unsigned long long* dst =
        (unsigned long long*)(copies + (size_t)(blockIdx.x & (NCOPY - 1)) * HSZ);
    for (int i = threadIdx.x; i < HSZ / 2; i += 256) {
        unsigned v0 = h[2 * i], v1 = h[2 * i + 1];
        if (v0 | v1)
            atomicAdd(&dst[i], (unsigned long long)v0 |
                               ((unsigned long long)v1 << 32));
    }
}

// ---------------- K2: sum 64 copies + per-class descending Jaccard scan + masked mean ----------------
// One block per class; 128 threads = 1 bucket each. Last block out computes the mean
// (deterministic: integer atomics only, loss in 2^53 fixed point).
__global__ __launch_bounds__(128) void scan_kernel(const unsigned* __restrict__ copies,
                                                   unsigned* __restrict__ lock,
                                                   unsigned long long* __restrict__ acc,
                                                   unsigned* __restrict__ npres,
                                                   float* __restrict__ out) {
    int c = blockIdx.x;
    int t = threadIdx.x;                 // 128 threads
    int bkt = NB - 1 - t;                // descending error order

    unsigned lo = 0, hi = 0;
#pragma unroll 8
    for (int y = 0; y < NCOPY; ++y) {
        unsigned v = copies[y * HSZ + c * NB + bkt];
        lo += v & 0xFFFFu;
        hi += v >> 16;
    }
    long long n_t = (long long)lo + (long long)hi;   // total in this bucket
    long long f_t = (long long)hi;                   // fg in this bucket

    __shared__ long long sn[NB], sf[NB];
    __shared__ long long totf;
    sn[t] = n_t; sf[t] = f_t;
    __syncthreads();
    if (t == 0) {
        long long an = 0, af = 0;
        for (int k = 0; k < NB; ++k) {
            long long nn = sn[k], ff = sf[k];
            sn[k] = an; sf[k] = af;       // exclusive prefix in descending order
            an += nn; af += ff;
        }
        totf = af;
    }
    __syncthreads();
    long long g = totf;

    double loss_t = 0.0;
    if (g > 0 && n_t > 0) {
        long long i  = sn[t], F  = sf[t];
        long long i2 = i + n_t, F2 = F + f_t;
        double Jp = 1.0 - (double)(g - F)  / (double)(g + i  - F);
        double Jn = 1.0 - (double)(g - F2) / (double)(g + i2 - F2);
        loss_t = ((double)bkt * (1.0 / (double)(NB - 1))) * (Jn - Jp);
    }

    __shared__ double sl[NB];
    sl[t] = loss_t;
    __syncthreads();
    for (int off = NB / 2; off > 0; off >>= 1) {
        if (t < off) sl[t] += sl[t + off];
        __syncthreads();
    }

    if (t == 0) {
        if (g > 0) {
            // fixed-point 2^53: loss in [0,1], 19 classes -> sum < 2^58, exact integer adds
            unsigned long long q =
                (unsigned long long)(long long)(sl[0] * 9007199254740992.0);
            atomicAdd(acc, q);
            atomicAdd(npres, 1u);
        }
        __threadfence();
        unsigned old = atomicAdd(lock, 1u);
        if (old == NCLS - 1) {                      // last block out does the mean
            unsigned long long a = atomicAdd(acc, 0ull);
            unsigned np = atomicAdd(npres, 0u);
            double s = (double)(long long)a * (1.0 / 9007199254740992.0);
            out[0] = (float)(s / (double)(np ? np : 1u));
        }
    }
}

extern "C" void kernel_launch(void* const* d_in, const int* in_sizes, int n_in,
                              void* d_out, int out_size, void* d_ws, size_t ws_size,
                              hipStream_t stream) {
    const float* logits = (const float*)d_in[0];
    const int*   labels = (const int*)d_in[1];
    float* out = (float*)d_out;

    unsigned* copies = (unsigned*)d_ws;                           // NCOPY*HSZ u32 = 622 KB
    unsigned long long* acc =
        (unsigned long long*)(((uintptr_t)(copies + (size_t)NCOPY * HSZ) + 15) & ~(uintptr_t)15);
    unsigned* lock  = (unsigned*)(acc + 1);
    unsigned* npres = lock + 1;

    zero_kernel<<<(NCOPY * HSZ) / 256, 256, 0, stream>>>(copies, acc, lock, npres);
    hist_kernel<<<NBLK, 256, 0, stream>>>(logits, labels, copies);
    scan_kernel<<<NCLS, NB, 0, stream>>>(copies, lock, acc, npres, out);
}

// Round 19
// 49.709 us; speedup vs baseline: 1.0847x; 1.0847x over previous
//
#include <hip/hip_runtime.h>

#define NB     128
#define NCLS   19
#define HW     (512*512)
#define NPIX   (8*HW)
#define HSZ    (NCLS*NB)          // 2432 packed u32 counters per histogram copy (9.7 KB)
#define NCOPY  64                 // L2-resident global copies (622 KB total)
#define NBLK   2048               // hist grid; 8 blocks/CU, 32 waves/CU

// ---------------- K0: zero the 64 copies + accumulators ----------------
__global__ __launch_bounds__(256) void zero_kernel(unsigned* __restrict__ copies,
                                                   unsigned long long* __restrict__ acc,
                                                   unsigned* __restrict__ lock,
                                                   unsigned* __restrict__ npres) {
    int i = blockIdx.x * 256 + threadIdx.x;       // NCOPY*HSZ = 608*256 exact
    copies[i] = 0u;
    if (i == 0) { *acc = 0ull; *lock = 0u; *npres = 0u; }
}

// ---------------- K1: softmax + LDS-private packed histogram, u64 atomic merge ----------------
// packed u32: low 16 = bg count, high 16 = fg count
// per-global-copy budget = 32 blocks * 1024 px = 32768 <= 65535 per field -> no overflow;
// u64 merge: word pair (2i, 2i+1) in one global_atomic_add_x2 -> same u32 layout,
// fields can't carry across (max 32768 < 65536).
// [TERMINAL CONFIG, measured best 49.54 us x2 (+ 49.67/49.68 siblings).
//  Falsified levers: partials round-trip, merge burst (u32/u64), load width
//  (float2/float4 at BOTH occupancies), LDS sub-copies, bank-conflict-free
//  transposed layout, contiguous DRAM spans, select-free binning, VALU trim,
//  single-kernel fusion (3 variants, spill- or sync-bound). hist ~= 40 us =
//  ~75% simultaneous utilization of HBM(27us floor) + VALU(~22us) + LDS-atomic
//  (~12us) pipes; remainder ~9 us = zero + merge + scan + 2 launch gaps.]
__global__ __launch_bounds__(256) void hist_kernel(const float* __restrict__ logits,
                                                   const int* __restrict__ labels,
                                                   unsigned* __restrict__ copies) {
    __shared__ unsigned h[HSZ];
    for (int i = threadIdx.x; i < HSZ; i += 256) h[i] = 0u;
    __syncthreads();

    int gt = blockIdx.x * 256 + threadIdx.x;
    const int stride = NBLK * 256;                 // total threads
#pragma unroll
    for (int it = 0; it < NPIX / (2 * stride); ++it) {   // = 2 iterations
        int p0 = (gt + it * stride) * 2;           // 2 consecutive pixels, 8B aligned
        int b  = p0 >> 18;                         // p0 / HW (HW = 2^18)
        int hw = p0 & (HW - 1);
        const float* base = logits + ((size_t)b * NCLS) * HW + hw;

        float e0[NCLS], e1[NCLS];
        float s0 = 0.f, s1 = 0.f;
#pragma unroll
        for (int c = 0; c < NCLS; ++c) {
            float2 z = *(const float2*)(base + (size_t)c * HW);  // coalesced 8B
            z.x = __expf(z.x);                     // no max-sub: |logit| < ~6 for N(0,1)
            z.y = __expf(z.y);
            e0[c] = z.x; e1[c] = z.y;
            s0 += z.x; s1 += z.y;
        }
        float sc0 = (float)(NB - 1) * __builtin_amdgcn_rcpf(s0);
        float sc1 = (float)(NB - 1) * __builtin_amdgcn_rcpf(s1);
        int2 lb = *(const int2*)(labels + p0);

#pragma unroll
        for (int c = 0; c < NCLS; ++c) {
            // bg bucket: floor(pc*(NB-1) + 0.5); fg: floor(NB - t) = round((1-pc)*(NB-1))
            float t0 = fmaf(e0[c], sc0, 0.5f);
            bool  f0 = (lb.x == c);
            t0 = f0 ? ((float)NB - t0) : t0;
            atomicAdd(&h[c * NB + (int)t0], f0 ? 0x10000u : 1u);

            float t1 = fmaf(e1[c], sc1, 0.5f);
            bool  f1 = (lb.y == c);
            t1 = f1 ? ((float)NB - t1) : t1;
            atomicAdd(&h[c * NB + (int)t1], f1 ? 0x10000u : 1u);
        }
    }

    __syncthreads();
    // merge into one of NCOPY L2-resident copies with u64 atomics (2 buckets/op)
    unsigned long long* dst =
        (unsigned long long*)(copies + (size_t)(blockIdx.x & (NCOPY - 1)) * HSZ);
    for (int i = threadIdx.x; i < HSZ / 2; i += 256) {
        unsigned v0 = h[2 * i], v1 = h[2 * i + 1];
        if (v0 | v1)
            atomicAdd(&dst[i], (unsigned long long)v0 |
                               ((unsigned long long)v1 << 32));
    }
}

// ---------------- K2: sum 64 copies + per-class descending Jaccard scan + masked mean ----------------
// One block per class; 128 threads = 1 bucket each. Last block out computes the mean
// (deterministic: integer atomics only, loss in 2^53 fixed point).
__global__ __launch_bounds__(128) void scan_kernel(const unsigned* __restrict__ copies,
                                                   unsigned* __restrict__ lock,
                                                   unsigned long long* __restrict__ acc,
                                                   unsigned* __restrict__ npres,
                                                   float* __restrict__ out) {
    int c = blockIdx.x;
    int t = threadIdx.x;                 // 128 threads
    int bkt = NB - 1 - t;                // descending error order

    unsigned lo = 0, hi = 0;
#pragma unroll 8
    for (int y = 0; y < NCOPY; ++y) {
        unsigned v = copies[y * HSZ + c * NB + bkt];
        lo += v & 0xFFFFu;
        hi += v >> 16;
    }
    long long n_t = (long long)lo + (long long)hi;   // total in this bucket
    long long f_t = (long long)hi;                   // fg in this bucket

    __shared__ long long sn[NB], sf[NB];
    __shared__ long long totf;
    sn[t] = n_t; sf[t] = f_t;
    __syncthreads();
    if (t == 0) {
        long long an = 0, af = 0;
        for (int k = 0; k < NB; ++k) {
            long long nn = sn[k], ff = sf[k];
            sn[k] = an; sf[k] = af;       // exclusive prefix in descending order
            an += nn; af += ff;
        }
        totf = af;
    }
    __syncthreads();
    long long g = totf;

    double loss_t = 0.0;
    if (g > 0 && n_t > 0) {
        long long i  = sn[t], F  = sf[t];
        long long i2 = i + n_t, F2 = F + f_t;
        double Jp = 1.0 - (double)(g - F)  / (double)(g + i  - F);
        double Jn = 1.0 - (double)(g - F2) / (double)(g + i2 - F2);
        loss_t = ((double)bkt * (1.0 / (double)(NB - 1))) * (Jn - Jp);
    }

    __shared__ double sl[NB];
    sl[t] = loss_t;
    __syncthreads();
    for (int off = NB / 2; off > 0; off >>= 1) {
        if (t < off) sl[t] += sl[t + off];
        __syncthreads();
    }

    if (t == 0) {
        if (g > 0) {
            // fixed-point 2^53: loss in [0,1], 19 classes -> sum < 2^58, exact integer adds
            unsigned long long q =
                (unsigned long long)(long long)(sl[0] * 9007199254740992.0);
            atomicAdd(acc, q);
            atomicAdd(npres, 1u);
        }
        __threadfence();
        unsigned old = atomicAdd(lock, 1u);
        if (old == NCLS - 1) {                      // last block out does the mean
            unsigned long long a = atomicAdd(acc, 0ull);
            unsigned np = atomicAdd(npres, 0u);
            double s = (double)(long long)a * (1.0 / 9007199254740992.0);
            out[0] = (float)(s / (double)(np ? np : 1u));
        }
    }
}

extern "C" void kernel_launch(void* const* d_in, const int* in_sizes, int n_in,
                              void* d_out, int out_size, void* d_ws, size_t ws_size,
                              hipStream_t stream) {
    const float* logits = (const float*)d_in[0];
    const int*   labels = (const int*)d_in[1];
    float* out = (float*)d_out;

    unsigned* copies = (unsigned*)d_ws;                           // NCOPY*HSZ u32 = 622 KB
    unsigned long long* acc =
        (unsigned long long*)(((uintptr_t)(copies + (size_t)NCOPY * HSZ) + 15) & ~(uintptr_t)15);
    unsigned* lock  = (unsigned*)(acc + 1);
    unsigned* npres = lock + 1;

    zero_kernel<<<(NCOPY * HSZ) / 256, 256, 0, stream>>>(copies, acc, lock, npres);
    hist_kernel<<<NBLK, 256, 0, stream>>>(logits, labels, copies);
    scan_kernel<<<NCLS, NB, 0, stream>>>(copies, lock, acc, npres, out);
}